// Round 5
// baseline (562.974 us; speedup 1.0000x reference)
//
#include <hip/hip_runtime.h>

#define N_TOK 2048
#define HD    1024
#define FD    4096
#define NE    8

typedef __attribute__((ext_vector_type(8))) short short8;
typedef __attribute__((ext_vector_type(4))) float floatx4;

// ---------- helpers ----------
__device__ __forceinline__ unsigned short f2bf(float f) {
  unsigned int u = __float_as_uint(f);
  u += 0x7fffu + ((u >> 16) & 1u);   // RNE
  return (unsigned short)(u >> 16);
}

__device__ __forceinline__ void gl2lds16(const unsigned short* g, unsigned short* l) {
  __builtin_amdgcn_global_load_lds(
      (const __attribute__((address_space(1))) unsigned int*)g,
      (__attribute__((address_space(3))) unsigned int*)l, 16, 0, 0);
}

__device__ __forceinline__ float gelu_tanh(float x) {
  float t = 0.7978845608028654f * x * (1.0f + 0.044715f * x * x);
  return 0.5f * x * (1.0f + tanhf(t));
}

__device__ __forceinline__ int poff_of(const int* __restrict__ cnt, int e) {
  int o = 0;
  for (int i = 0; i < e; ++i) o += (cnt[i] + 127) & ~127;
  return o;
}

// ---------- gating ----------
__global__ void k_gating(const float* __restrict__ x, const float* __restrict__ wg,
                         float* __restrict__ p) {
  int wave = threadIdx.x >> 6;
  int lane = threadIdx.x & 63;
  int n = blockIdx.x * 4 + wave;
  const float4* xr = (const float4*)(x + (size_t)n * HD);
  float4 xv[4];
  #pragma unroll
  for (int i = 0; i < 4; ++i) xv[i] = xr[lane + i * 64];
  for (int e = 0; e < NE; ++e) {
    const float4* wr = (const float4*)(wg + (size_t)e * HD);
    float s = 0.f;
    #pragma unroll
    for (int i = 0; i < 4; ++i) {
      float4 w4 = wr[lane + i * 64];
      s += xv[i].x * w4.x + xv[i].y * w4.y + xv[i].z * w4.z + xv[i].w * w4.w;
    }
    for (int o = 32; o > 0; o >>= 1) s += __shfl_xor(s, o, 64);
    if (lane == 0) p[e * N_TOK + n] = s;
  }
}

// ---------- softmax over axis=0 ----------
__global__ void k_softmax(float* __restrict__ p) {
  int e = blockIdx.x;
  float* col = p + e * N_TOK;
  __shared__ float red[256];
  int t = threadIdx.x;
  float m = -1e30f;
  for (int i = t; i < N_TOK; i += 256) m = fmaxf(m, col[i]);
  red[t] = m; __syncthreads();
  for (int s = 128; s > 0; s >>= 1) { if (t < s) red[t] = fmaxf(red[t], red[t + s]); __syncthreads(); }
  m = red[0]; __syncthreads();
  float sum = 0.f;
  for (int i = t; i < N_TOK; i += 256) { float v = expf(col[i] - m); col[i] = v; sum += v; }
  red[t] = sum; __syncthreads();
  for (int s = 128; s > 0; s >>= 1) { if (t < s) red[t] += red[t + s]; __syncthreads(); }
  float inv = 1.0f / red[0];
  for (int i = t; i < N_TOK; i += 256) col[i] *= inv;
}

// ---------- routing ----------
__global__ void k_route(const int* __restrict__ mp, const float* __restrict__ p,
                        int* __restrict__ cnt, int* __restrict__ idxl,
                        int* __restrict__ tke, int* __restrict__ tks, float* __restrict__ tkw) {
  int n = blockIdx.x * 256 + threadIdx.x;
  if (n >= N_TOK) return;
  int m0 = mp[n * 2 + 0], m1 = mp[n * 2 + 1];
  if (m0 == m1) {
    int s = atomicAdd(&cnt[m0], 1);
    idxl[m0 * N_TOK + s] = n;
    tke[n * 2] = m0; tks[n * 2] = s; tkw[n * 2] = 1.0f;
    tke[n * 2 + 1] = m0; tks[n * 2 + 1] = s; tkw[n * 2 + 1] = 0.0f;
  } else {
    float p0 = p[m0 * N_TOK + n], p1 = p[m1 * N_TOK + n];
    float inv = 1.0f / (p0 + p1);
    int s0 = atomicAdd(&cnt[m0], 1);
    idxl[m0 * N_TOK + s0] = n;
    tke[n * 2] = m0; tks[n * 2] = s0; tkw[n * 2] = p0 * inv;
    int s1 = atomicAdd(&cnt[m1], 1);
    idxl[m1 * N_TOK + s1] = n;
    tke[n * 2 + 1] = m1; tks[n * 2 + 1] = s1; tkw[n * 2 + 1] = p1 * inv;
  }
}

// ---------- gather x rows -> bf16 arena ----------
__global__ void k_gather(const float* __restrict__ x, const int* __restrict__ cnt,
                         const int* __restrict__ idxl, unsigned short* __restrict__ xg) {
  int e = blockIdx.y;
  int r = blockIdx.x;
  int c = cnt[e];
  int pc = (c + 127) & ~127;
  if (r >= pc) return;
  unsigned short* dst = xg + ((size_t)poff_of(cnt, e) + r) * HD;
  int t = threadIdx.x;
  union { unsigned short us[8]; uint4 v; } o;
  if (r < c) {
    const float* src = x + (size_t)idxl[e * N_TOK + r] * HD;
    float4 f0 = ((const float4*)src)[t * 2];
    float4 f1 = ((const float4*)src)[t * 2 + 1];
    o.us[0] = f2bf(f0.x); o.us[1] = f2bf(f0.y); o.us[2] = f2bf(f0.z); o.us[3] = f2bf(f0.w);
    o.us[4] = f2bf(f1.x); o.us[5] = f2bf(f1.y); o.us[6] = f2bf(f1.z); o.us[7] = f2bf(f1.w);
  } else {
    o.v.x = 0u; o.v.y = 0u; o.v.z = 0u; o.v.w = 0u;
  }
  ((uint4*)dst)[t] = o.v;
}

// ---------- GEMM1: h = gelu(xg @ W1[e] + b1[e]) ----------
// 64m x 128n, BK=32, 4 waves (each 64m x 32n). B consumed DIRECTLY from fp32
// W1 [K][N]: waves 0-1 reg-stage (8 coalesced row loads -> f2bf -> 4 swizzled
// ds_write_b128 into [n][32k]); waves 2-3 stage A via gl2lds. No pre-pass.
// Block index XCD-pinned: all m-tiles of one (e,nt) B-panel share an XCD so
// panel re-reads hit that XCD's L2.
__global__ __launch_bounds__(256) void k_gemm1(
    const unsigned short* __restrict__ xg, const float* __restrict__ w1,
    const float* __restrict__ b1, const int* __restrict__ cnt,
    unsigned short* __restrict__ h) {
  const int b = blockIdx.x;
  const int xcd = b & 7;
  const int idx = b >> 3;
  const int m = idx & 31;                  // m-tile within expert
  const int panel = ((idx >> 5) << 3) + xcd;  // 0..255
  const int e  = panel >> 5;
  const int nt = panel & 31;

  const int c = cnt[e];
  if (m * 64 >= c) return;
  const int po = poff_of(cnt, e);
  const int nbase = nt * 128;
  const size_t arow0 = (size_t)po + m * 64;

  const unsigned short* A = xg + arow0 * HD;
  const float* Bsrc = w1 + (size_t)e * HD * FD + nbase;

  __shared__ unsigned short As[64 * 32];    // [64m][32k]
  __shared__ unsigned short Bs[128 * 32];   // [128n][32k], chunk-XOR swizzled

  const int tid = threadIdx.x;
  const int wave = tid >> 6, lane = tid & 63;
  const int quad = lane >> 4, lrow = lane & 15;
  const int wn = wave * 32;

  floatx4 acc[4][2];
  #pragma unroll
  for (int i = 0; i < 4; ++i)
    #pragma unroll
    for (int j = 0; j < 2; ++j) acc[i][j] = (floatx4){0.f, 0.f, 0.f, 0.f};

  const int bg = tid & 31;            // n-group (4 cols)
  const int bq = (tid >> 5) & 3;      // k-octet (8 rows)

  for (int kt = 0; kt < HD / 32; ++kt) {
    __syncthreads();
    if (tid < 128) {
      // B: read 8k x 4n fp32 block, cast, write 4 swizzled b128
      float4 f[8];
      const float* src = Bsrc + (size_t)(kt * 32 + bq * 8) * FD + bg * 4;
      #pragma unroll
      for (int j = 0; j < 8; ++j)
        f[j] = *(const float4*)(src + (size_t)j * FD);
      #pragma unroll
      for (int jn = 0; jn < 4; ++jn) {
        int n = bg * 4 + jn;
        union { unsigned short us[8]; uint4 v; } u;
        #pragma unroll
        for (int j = 0; j < 8; ++j) u.us[j] = f2bf(((const float*)&f[j])[jn]);
        *(uint4*)(Bs + n * 32 + 8 * (bq ^ (bg & 3))) = u.v;
      }
    } else {
      // A: 256 chunks of 16B via gl2lds (linear [64m][32k])
      #pragma unroll
      for (int i = 0; i < 2; ++i) {
        int base = ((wave - 2) << 7) + (i << 6);     // wave-uniform chunk base
        int ch = base + (tid & 63);
        int row = ch >> 2, ko = (ch & 3) * 8;
        gl2lds16(A + (size_t)row * HD + kt * 32 + ko, As + (size_t)base * 8);
      }
    }
    __syncthreads();
    short8 aF[4], bF[2];
    #pragma unroll
    for (int i = 0; i < 4; ++i)
      aF[i] = *(const short8*)(As + (i * 16 + lrow) * 32 + quad * 8);
    #pragma unroll
    for (int j = 0; j < 2; ++j) {
      int n = wn + j * 16 + lrow;
      bF[j] = *(const short8*)(Bs + n * 32 + 8 * (quad ^ ((n >> 2) & 3)));
    }
    #pragma unroll
    for (int i = 0; i < 4; ++i)
      #pragma unroll
      for (int j = 0; j < 2; ++j)
        acc[i][j] = __builtin_amdgcn_mfma_f32_16x16x32_bf16(aF[i], bF[j], acc[i][j], 0, 0, 0);
  }

  #pragma unroll
  for (int i = 0; i < 4; ++i) {
    #pragma unroll
    for (int rr = 0; rr < 4; ++rr) {
      int row = i * 16 + quad * 4 + rr;
      unsigned short* hr = h + (arow0 + row) * FD + nbase;
      #pragma unroll
      for (int j = 0; j < 2; ++j) {
        int col = wn + j * 16 + lrow;
        float v = acc[i][j][rr] + b1[e * FD + nbase + col];
        hr[col] = f2bf(gelu_tanh(v));
      }
    }
  }
}

// ---------- GEMM2: ya = h @ W2[e]  (64m x 64n, BK=64) ----------
// Same reg-staged fp32 B path (W2 is [K=F][N=H] natively); two 32k halves.
__global__ __launch_bounds__(256) void k_gemm2(
    const unsigned short* __restrict__ h, const float* __restrict__ w2,
    const int* __restrict__ cnt, unsigned short* __restrict__ ya) {
  const int b = blockIdx.x;
  const int xcd = b & 7;
  const int idx = b >> 3;
  const int m = idx & 31;
  const int panel = ((idx >> 5) << 3) + xcd;  // 0..127
  const int e  = panel >> 4;
  const int nt = panel & 15;

  const int c = cnt[e];
  if (m * 64 >= c) return;
  const int po = poff_of(cnt, e);
  const int nbase = nt * 64;
  const size_t arow0 = (size_t)po + m * 64;

  const unsigned short* A = h + arow0 * FD;
  const float* Bsrc = w2 + (size_t)e * FD * HD + nbase;

  __shared__ unsigned short As[2][64 * 32];   // [half][64m][32k]
  __shared__ unsigned short Bs[2][64 * 32];   // [half][64n][32k], swizzled

  const int tid = threadIdx.x;
  const int wave = tid >> 6, lane = tid & 63;
  const int quad = lane >> 4, lrow = lane & 15;
  const int wm = (wave >> 1) * 32, wn = (wave & 1) * 32;

  floatx4 acc[2][2];
  #pragma unroll
  for (int i = 0; i < 2; ++i)
    #pragma unroll
    for (int j = 0; j < 2; ++j) acc[i][j] = (floatx4){0.f, 0.f, 0.f, 0.f};

  const int bg = tid & 15;            // n-group (4 cols of 64)
  const int bq = (tid >> 4) & 7;      // k-octet (8 rows of 64)
  const int bh = bq >> 2, bq2 = bq & 3;

  for (int kt = 0; kt < FD / 64; ++kt) {
    __syncthreads();
    if (tid < 128) {
      float4 f[8];
      const float* src = Bsrc + (size_t)(kt * 64 + bq * 8) * HD + bg * 4;
      #pragma unroll
      for (int j = 0; j < 8; ++j)
        f[j] = *(const float4*)(src + (size_t)j * HD);
      #pragma unroll
      for (int jn = 0; jn < 4; ++jn) {
        int n = bg * 4 + jn;
        union { unsigned short us[8]; uint4 v; } u;
        #pragma unroll
        for (int j = 0; j < 8; ++j) u.us[j] = f2bf(((const float*)&f[j])[jn]);
        *(uint4*)(Bs[bh] + n * 32 + 8 * (bq2 ^ (bg & 3))) = u.v;
      }
    } else {
      // A: 512 chunks ([64m][64k] split into two [64m][32k] halves)
      #pragma unroll
      for (int i = 0; i < 4; ++i) {
        int half = i >> 1;
        int base = ((i & 1) << 7) + ((wave & 1) << 6);
        int ch = base + (tid & 63);
        int row = ch >> 2, ko = (ch & 3) * 8 + half * 32;
        gl2lds16(A + (size_t)row * FD + kt * 64 + ko, As[half] + (size_t)base * 8);
      }
    }
    __syncthreads();
    #pragma unroll
    for (int cc = 0; cc < 2; ++cc) {
      short8 aF[2], bF[2];
      #pragma unroll
      for (int i = 0; i < 2; ++i)
        aF[i] = *(const short8*)(As[cc] + (wm + i * 16 + lrow) * 32 + quad * 8);
      #pragma unroll
      for (int j = 0; j < 2; ++j) {
        int n = wn + j * 16 + lrow;
        bF[j] = *(const short8*)(Bs[cc] + n * 32 + 8 * (quad ^ ((n >> 2) & 3)));
      }
      #pragma unroll
      for (int i = 0; i < 2; ++i)
        #pragma unroll
        for (int j = 0; j < 2; ++j)
          acc[i][j] = __builtin_amdgcn_mfma_f32_16x16x32_bf16(aF[i], bF[j], acc[i][j], 0, 0, 0);
    }
  }

  #pragma unroll
  for (int i = 0; i < 2; ++i) {
    #pragma unroll
    for (int rr = 0; rr < 4; ++rr) {
      size_t row = arow0 + wm + i * 16 + quad * 4 + rr;
      unsigned short* yr = ya + row * HD + nbase;
      #pragma unroll
      for (int j = 0; j < 2; ++j) {
        int col = wn + j * 16 + lrow;
        yr[col] = f2bf(acc[i][j][rr]);
      }
    }
  }
}

// ---------- combine ----------
__global__ __launch_bounds__(256) void k_combine(
    const unsigned short* __restrict__ ya, const float* __restrict__ b2,
    const int* __restrict__ cnt, const int* __restrict__ tke,
    const int* __restrict__ tks, const float* __restrict__ tkw,
    float* __restrict__ out) {
  int n = blockIdx.x;
  int e0 = tke[n * 2], e1 = tke[n * 2 + 1];
  int p0 = poff_of(cnt, e0) + tks[n * 2];
  int p1 = poff_of(cnt, e1) + tks[n * 2 + 1];
  float w0 = tkw[n * 2], w1 = tkw[n * 2 + 1];
  int c = threadIdx.x * 4;
  union { unsigned short us[4]; unsigned long long ll; } y0, y1;
  y0.ll = *(const unsigned long long*)(ya + (size_t)p0 * HD + c);
  y1.ll = *(const unsigned long long*)(ya + (size_t)p1 * HD + c);
  float4 bb0 = *(const float4*)(b2 + (size_t)e0 * HD + c);
  float4 bb1 = *(const float4*)(b2 + (size_t)e1 * HD + c);
  float4 o;
  o.x = w0 * (__uint_as_float((unsigned)y0.us[0] << 16) + bb0.x) + w1 * (__uint_as_float((unsigned)y1.us[0] << 16) + bb1.x);
  o.y = w0 * (__uint_as_float((unsigned)y0.us[1] << 16) + bb0.y) + w1 * (__uint_as_float((unsigned)y1.us[1] << 16) + bb1.y);
  o.z = w0 * (__uint_as_float((unsigned)y0.us[2] << 16) + bb0.z) + w1 * (__uint_as_float((unsigned)y1.us[2] << 16) + bb1.z);
  o.w = w0 * (__uint_as_float((unsigned)y0.us[3] << 16) + bb0.w) + w1 * (__uint_as_float((unsigned)y1.us[3] << 16) + bb1.w);
  *(float4*)(out + (size_t)n * HD + c) = o;
}

// ---------- launch ----------
extern "C" void kernel_launch(void* const* d_in, const int* in_sizes, int n_in,
                              void* d_out, int out_size, void* d_ws, size_t ws_size,
                              hipStream_t stream) {
  const float* x  = (const float*)d_in[0];
  const int*   mp = (const int*)d_in[1];
  const float* wg = (const float*)d_in[2];
  const float* w1 = (const float*)d_in[3];
  const float* b1 = (const float*)d_in[4];
  const float* w2 = (const float*)d_in[5];
  const float* b2 = (const float*)d_in[6];
  float* out = (float*)d_out;
  char* ws = (char*)d_ws;

  float* p    = (float*)(ws + 0);            // 65536
  int*   cnt  = (int*)(ws + 65536);          // 32
  int*   idxl = (int*)(ws + 66048);          // 65536
  int*   tke  = (int*)(ws + 131584);         // 16384
  int*   tks  = (int*)(ws + 147968);         // 16384
  float* tkw  = (float*)(ws + 164352);       // 16384
  size_t off = 180736;
  unsigned short* xg  = (unsigned short*)(ws + off);  off += 10485760;   // 5120*1024*2
  unsigned short* h   = (unsigned short*)(ws + off);  off += 41943040;   // 5120*4096*2
  unsigned short* ya  = (unsigned short*)(ws + off);  off += 10485760;   // 5120*1024*2

  hipMemsetAsync(cnt, 0, 32, stream);

  k_gating<<<512, 256, 0, stream>>>(x, wg, p);
  k_softmax<<<NE, 256, 0, stream>>>(p);
  k_route<<<NE, 256, 0, stream>>>(mp, p, cnt, idxl, tke, tks, tkw);
  k_gather<<<dim3(N_TOK, NE), 128, 0, stream>>>(x, cnt, idxl, xg);
  k_gemm1<<<8192, 256, 0, stream>>>(xg, w1, b1, cnt, h);
  k_gemm2<<<4096, 256, 0, stream>>>(h, w2, cnt, ya);
  k_combine<<<N_TOK, 256, 0, stream>>>(ya, b2, cnt, tke, tks, tkw, out);
}

// Round 6
// 492.024 us; speedup vs baseline: 1.1442x; 1.1442x over previous
//
#include <hip/hip_runtime.h>

#define N_TOK 2048
#define HD    1024
#define FD    4096
#define NE    8

typedef __attribute__((ext_vector_type(8))) short short8;
typedef __attribute__((ext_vector_type(4))) float floatx4;

// ---------- helpers ----------
__device__ __forceinline__ unsigned short f2bf(float f) {
  unsigned int u = __float_as_uint(f);
  u += 0x7fffu + ((u >> 16) & 1u);   // RNE
  return (unsigned short)(u >> 16);
}

__device__ __forceinline__ void gl2lds16(const unsigned short* g, unsigned short* l) {
  __builtin_amdgcn_global_load_lds(
      (const __attribute__((address_space(1))) unsigned int*)g,
      (__attribute__((address_space(3))) unsigned int*)l, 16, 0, 0);
}

__device__ __forceinline__ float gelu_tanh(float x) {
  float t = 0.7978845608028654f * x * (1.0f + 0.044715f * x * x);
  return 0.5f * x * (1.0f + tanhf(t));
}

__device__ __forceinline__ int poff_of(const int* __restrict__ cnt, int e) {
  int o = 0;
  for (int i = 0; i < e; ++i) o += (cnt[i] + 127) & ~127;
  return o;
}

// ---------- gating ----------
__global__ void k_gating(const float* __restrict__ x, const float* __restrict__ wg,
                         float* __restrict__ p) {
  int wave = threadIdx.x >> 6;
  int lane = threadIdx.x & 63;
  int n = blockIdx.x * 4 + wave;
  const float4* xr = (const float4*)(x + (size_t)n * HD);
  float4 xv[4];
  #pragma unroll
  for (int i = 0; i < 4; ++i) xv[i] = xr[lane + i * 64];
  for (int e = 0; e < NE; ++e) {
    const float4* wr = (const float4*)(wg + (size_t)e * HD);
    float s = 0.f;
    #pragma unroll
    for (int i = 0; i < 4; ++i) {
      float4 w4 = wr[lane + i * 64];
      s += xv[i].x * w4.x + xv[i].y * w4.y + xv[i].z * w4.z + xv[i].w * w4.w;
    }
    for (int o = 32; o > 0; o >>= 1) s += __shfl_xor(s, o, 64);
    if (lane == 0) p[e * N_TOK + n] = s;
  }
}

// ---------- softmax over axis=0 ----------
__global__ void k_softmax(float* __restrict__ p) {
  int e = blockIdx.x;
  float* col = p + e * N_TOK;
  __shared__ float red[256];
  int t = threadIdx.x;
  float m = -1e30f;
  for (int i = t; i < N_TOK; i += 256) m = fmaxf(m, col[i]);
  red[t] = m; __syncthreads();
  for (int s = 128; s > 0; s >>= 1) { if (t < s) red[t] = fmaxf(red[t], red[t + s]); __syncthreads(); }
  m = red[0]; __syncthreads();
  float sum = 0.f;
  for (int i = t; i < N_TOK; i += 256) { float v = expf(col[i] - m); col[i] = v; sum += v; }
  red[t] = sum; __syncthreads();
  for (int s = 128; s > 0; s >>= 1) { if (t < s) red[t] += red[t + s]; __syncthreads(); }
  float inv = 1.0f / red[0];
  for (int i = t; i < N_TOK; i += 256) col[i] *= inv;
}

// ---------- routing: arena lists + token-indexed (expert,slot,weight) ----------
__global__ void k_route(const int* __restrict__ mp, const float* __restrict__ p,
                        int* __restrict__ cnt, int* __restrict__ idxl,
                        int* __restrict__ tke, int* __restrict__ tks, float* __restrict__ tkw) {
  int n = blockIdx.x * 256 + threadIdx.x;
  if (n >= N_TOK) return;
  int m0 = mp[n * 2 + 0], m1 = mp[n * 2 + 1];
  if (m0 == m1) {
    int s = atomicAdd(&cnt[m0], 1);
    idxl[m0 * N_TOK + s] = n;
    tke[n * 2] = m0; tks[n * 2] = s; tkw[n * 2] = 1.0f;
    tke[n * 2 + 1] = m0; tks[n * 2 + 1] = s; tkw[n * 2 + 1] = 0.0f;
  } else {
    float p0 = p[m0 * N_TOK + n], p1 = p[m1 * N_TOK + n];
    float inv = 1.0f / (p0 + p1);
    int s0 = atomicAdd(&cnt[m0], 1);
    idxl[m0 * N_TOK + s0] = n;
    tke[n * 2] = m0; tks[n * 2] = s0; tkw[n * 2] = p0 * inv;
    int s1 = atomicAdd(&cnt[m1], 1);
    idxl[m1 * N_TOK + s1] = n;
    tke[n * 2 + 1] = m1; tks[n * 2 + 1] = s1; tkw[n * 2 + 1] = p1 * inv;
  }
}

// ---------- gather x rows -> bf16 arena ----------
__global__ void k_gather(const float* __restrict__ x, const int* __restrict__ cnt,
                         const int* __restrict__ idxl, unsigned short* __restrict__ xg) {
  int e = blockIdx.y;
  int r = blockIdx.x;
  int c = cnt[e];
  int pc = (c + 127) & ~127;
  if (r >= pc) return;
  unsigned short* dst = xg + ((size_t)poff_of(cnt, e) + r) * HD;
  int t = threadIdx.x;
  union { unsigned short us[8]; uint4 v; } o;
  if (r < c) {
    const float* src = x + (size_t)idxl[e * N_TOK + r] * HD;
    float4 f0 = ((const float4*)src)[t * 2];
    float4 f1 = ((const float4*)src)[t * 2 + 1];
    o.us[0] = f2bf(f0.x); o.us[1] = f2bf(f0.y); o.us[2] = f2bf(f0.z); o.us[3] = f2bf(f0.w);
    o.us[4] = f2bf(f1.x); o.us[5] = f2bf(f1.y); o.us[6] = f2bf(f1.z); o.us[7] = f2bf(f1.w);
  } else {
    o.v.x = 0u; o.v.y = 0u; o.v.z = 0u; o.v.w = 0u;
  }
  ((uint4*)dst)[t] = o.v;
}

// ---------- transpose+cvt into GEMM-native 8KB tiles, REGISTER transpose ----------
// Layout: w1t[e][nt(32)][kt(32)][128n][32k], w2t[e][nt(8)][kt(128)][128n][32k].
// No LDS, no barrier: each thread owns an 8k x 4n block -- 8 coalesced float4
// row loads (256B segments), 32 f2bf casts in registers, 4 uint4 stores into
// the tiled output (64B segments inside fully-written 16KB tiles).
__global__ __launch_bounds__(256) void k_transtile(const float* __restrict__ w1,
                                                   unsigned short* __restrict__ w1t,
                                                   const float* __restrict__ w2,
                                                   unsigned short* __restrict__ w2t) {
  int l = blockIdx.x;
  const float* src; unsigned short* dst; int ncols; size_t tb0, tb1;
  int kt, ng;
  if (l < 4096) {        // W1: K=HD rows, N=FD cols
    int e = l >> 9; kt = (l >> 4) & 31; ng = l & 15;
    src = w1 + (size_t)e * HD * FD; ncols = FD; dst = w1t;
    tb0 = (((size_t)e * 32 + ng * 2 + 0) * 32 + kt) * 4096;
    tb1 = (((size_t)e * 32 + ng * 2 + 1) * 32 + kt) * 4096;
  } else {               // W2: K=FD rows, N=HD cols
    int l2 = l - 4096;
    int e = l2 >> 9; kt = (l2 >> 2) & 127; ng = l2 & 3;
    src = w2 + (size_t)e * FD * HD; ncols = HD; dst = w2t;
    tb0 = (((size_t)e * 8 + ng * 2 + 0) * 128 + kt) * 4096;
    tb1 = (((size_t)e * 8 + ng * 2 + 1) * 128 + kt) * 4096;
  }
  const int t = threadIdx.x;
  const int k0 = (t & 3) * 8;        // k-octet 0..24
  const int n0 = (t >> 2) * 4;       // n 0..252
  const float* s = src + (size_t)(kt * 32 + k0) * ncols + ng * 256 + n0;
  float4 f[8];
  #pragma unroll
  for (int j = 0; j < 8; ++j)
    f[j] = *(const float4*)(s + (size_t)j * ncols);
  size_t tb = (n0 < 128) ? tb0 : tb1;
  unsigned short* d = dst + tb + (size_t)(n0 & 127) * 32 + k0;
  #pragma unroll
  for (int i = 0; i < 4; ++i) {
    union { unsigned short us[8]; uint4 v; } u;
    #pragma unroll
    for (int j = 0; j < 8; ++j) u.us[j] = f2bf(((const float*)&f[j])[i]);
    *(uint4*)(d + (size_t)i * 32) = u.v;
  }
}

// ---------- GEMM1: h = gelu(xg @ W1[e] + b1[e])  (K=1024, tile 64x128) ----------
__global__ __launch_bounds__(256) void k_gemm1(
    const unsigned short* __restrict__ xg, const unsigned short* __restrict__ w1t,
    const float* __restrict__ b1, const int* __restrict__ cnt,
    unsigned short* __restrict__ h) {
  const int l = blockIdx.x;
  const int r = l & 7;
  const int m = (l >> 3) & 31;
  const int q = l >> 8;
  const int e = q >> 2;
  const int n = ((q & 3) << 3) | r;

  const int c = cnt[e];
  const int mbase = m * 64;
  if (mbase >= c) return;
  const int nbase = n * 128;
  const int po = poff_of(cnt, e);
  const unsigned short* A = xg + ((size_t)po + mbase) * HD;
  const unsigned short* Bt = w1t + (((size_t)e * 32 + n) * 32) * 4096;  // tiled B

  __shared__ unsigned short As[64 * 32];
  __shared__ unsigned short Bs[128 * 32];

  const int tid = threadIdx.x;
  const int wave = tid >> 6, lane = tid & 63;
  const int quad = lane >> 4, lrow = lane & 15;
  const int wn = wave * 32;

  floatx4 acc[4][2];
  #pragma unroll
  for (int i = 0; i < 4; ++i)
    #pragma unroll
    for (int j = 0; j < 2; ++j) acc[i][j] = (floatx4){0.f, 0.f, 0.f, 0.f};

  const int rA = tid >> 2, kA = (tid & 3) * 8;

  for (int kt = 0; kt < HD / 32; ++kt) {
    __syncthreads();
    gl2lds16(A + kt * 32 + (size_t)rA * HD + kA, As + (size_t)wave * 512);
    const unsigned short* gb = Bt + (size_t)kt * 4096 + (size_t)tid * 8;
    gl2lds16(gb,        Bs + (size_t)wave * 512);
    gl2lds16(gb + 2048, Bs + 2048 + (size_t)wave * 512);
    __syncthreads();
    short8 aF[4], bF[2];
    #pragma unroll
    for (int i = 0; i < 4; ++i)
      aF[i] = *(const short8*)(As + (i * 16 + lrow) * 32 + quad * 8);
    #pragma unroll
    for (int j = 0; j < 2; ++j)
      bF[j] = *(const short8*)(Bs + (wn + j * 16 + lrow) * 32 + quad * 8);
    #pragma unroll
    for (int i = 0; i < 4; ++i)
      #pragma unroll
      for (int j = 0; j < 2; ++j)
        acc[i][j] = __builtin_amdgcn_mfma_f32_16x16x32_bf16(aF[i], bF[j], acc[i][j], 0, 0, 0);
  }

  const size_t hrow0 = (size_t)po + mbase;
  #pragma unroll
  for (int i = 0; i < 4; ++i) {
    #pragma unroll
    for (int rr = 0; rr < 4; ++rr) {
      int row = i * 16 + quad * 4 + rr;
      unsigned short* hr = h + (hrow0 + row) * FD + nbase;
      #pragma unroll
      for (int j = 0; j < 2; ++j) {
        int col = wn + j * 16 + lrow;
        float v = acc[i][j][rr] + b1[e * FD + nbase + col];
        hr[col] = f2bf(gelu_tanh(v));
      }
    }
  }
}

// ---------- GEMM2: ya = h @ W2[e]  (K=4096, tile 64x64, BK=64) ----------
__global__ __launch_bounds__(256) void k_gemm2(
    const unsigned short* __restrict__ h, const unsigned short* __restrict__ w2t,
    const int* __restrict__ cnt, unsigned short* __restrict__ ya) {
  const int l = blockIdx.x;
  const int nt = l & 15;
  const int mt = l >> 4;
  const int mbase = mt * 64;
  const int nbase = nt * 64;

  // expert lookup over padded row space
  int e = -1, po = 0, ce = 0;
  {
    int o = 0;
    #pragma unroll
    for (int i = 0; i < NE; ++i) {
      int ci = cnt[i];
      int pc = (ci + 127) & ~127;
      if (mbase >= o && mbase < o + pc) { e = i; po = o; ce = ci; }
      o += pc;
    }
  }
  if (e < 0) return;                 // beyond padded total
  if (mbase - po >= ce) return;      // pure pad tile

  const unsigned short* A = h + (size_t)mbase * FD;
  // tiled B: 64-row half (nt&1) of 128-tile (nt>>1)
  const unsigned short* Bt = w2t + (((size_t)e * 8 + (nt >> 1)) * 128) * 4096
                                 + (size_t)(nt & 1) * 2048;

  __shared__ unsigned short As[2 * 64 * 32];   // [c][64n][32k]
  __shared__ unsigned short Bs[2 * 64 * 32];

  const int tid = threadIdx.x;
  const int wave = tid >> 6, lane = tid & 63;
  const int quad = lane >> 4, lrow = lane & 15;
  const int wm = (wave >> 1) * 32, wn = (wave & 1) * 32;

  floatx4 acc[2][2];
  #pragma unroll
  for (int i = 0; i < 2; ++i)
    #pragma unroll
    for (int j = 0; j < 2; ++j) acc[i][j] = (floatx4){0.f, 0.f, 0.f, 0.f};

  const int r0 = tid >> 2, k0 = (tid & 3) * 8;

  for (int kt = 0; kt < FD / 64; ++kt) {
    __syncthreads();
    #pragma unroll
    for (int cc = 0; cc < 2; ++cc) {
      gl2lds16(A + (size_t)r0 * FD + kt * 64 + cc * 32 + k0,
               As + cc * 2048 + (size_t)wave * 512);
      gl2lds16(Bt + (size_t)(kt * 2 + cc) * 4096 + (size_t)tid * 8,
               Bs + cc * 2048 + (size_t)wave * 512);
    }
    __syncthreads();
    #pragma unroll
    for (int cc = 0; cc < 2; ++cc) {
      short8 aF[2], bF[2];
      #pragma unroll
      for (int i = 0; i < 2; ++i)
        aF[i] = *(const short8*)(As + cc * 2048 + (wm + i * 16 + lrow) * 32 + quad * 8);
      #pragma unroll
      for (int j = 0; j < 2; ++j)
        bF[j] = *(const short8*)(Bs + cc * 2048 + (wn + j * 16 + lrow) * 32 + quad * 8);
      #pragma unroll
      for (int i = 0; i < 2; ++i)
        #pragma unroll
        for (int j = 0; j < 2; ++j)
          acc[i][j] = __builtin_amdgcn_mfma_f32_16x16x32_bf16(aF[i], bF[j], acc[i][j], 0, 0, 0);
    }
  }

  #pragma unroll
  for (int i = 0; i < 2; ++i) {
    #pragma unroll
    for (int rr = 0; rr < 4; ++rr) {
      int row = mbase + wm + i * 16 + quad * 4 + rr;
      unsigned short* yr = ya + (size_t)row * HD + nbase;
      #pragma unroll
      for (int j = 0; j < 2; ++j) {
        int col = wn + j * 16 + lrow;
        yr[col] = f2bf(acc[i][j][rr]);
      }
    }
  }
}

// ---------- combine: out[n] = sum_k w_k * (ya[pos_k] + b2[e_k]) ----------
__global__ __launch_bounds__(256) void k_combine(
    const unsigned short* __restrict__ ya, const float* __restrict__ b2,
    const int* __restrict__ cnt, const int* __restrict__ tke,
    const int* __restrict__ tks, const float* __restrict__ tkw,
    float* __restrict__ out) {
  int n = blockIdx.x;
  int e0 = tke[n * 2], e1 = tke[n * 2 + 1];
  int p0 = poff_of(cnt, e0) + tks[n * 2];
  int p1 = poff_of(cnt, e1) + tks[n * 2 + 1];
  float w0 = tkw[n * 2], w1 = tkw[n * 2 + 1];
  int c = threadIdx.x * 4;
  union { unsigned short us[4]; unsigned long long ll; } y0, y1;
  y0.ll = *(const unsigned long long*)(ya + (size_t)p0 * HD + c);
  y1.ll = *(const unsigned long long*)(ya + (size_t)p1 * HD + c);
  float4 bb0 = *(const float4*)(b2 + (size_t)e0 * HD + c);
  float4 bb1 = *(const float4*)(b2 + (size_t)e1 * HD + c);
  float4 o;
  o.x = w0 * (__uint_as_float((unsigned)y0.us[0] << 16) + bb0.x) + w1 * (__uint_as_float((unsigned)y1.us[0] << 16) + bb1.x);
  o.y = w0 * (__uint_as_float((unsigned)y0.us[1] << 16) + bb0.y) + w1 * (__uint_as_float((unsigned)y1.us[1] << 16) + bb1.y);
  o.z = w0 * (__uint_as_float((unsigned)y0.us[2] << 16) + bb0.z) + w1 * (__uint_as_float((unsigned)y1.us[2] << 16) + bb1.z);
  o.w = w0 * (__uint_as_float((unsigned)y0.us[3] << 16) + bb0.w) + w1 * (__uint_as_float((unsigned)y1.us[3] << 16) + bb1.w);
  *(float4*)(out + (size_t)n * HD + c) = o;
}

// ---------- launch ----------
extern "C" void kernel_launch(void* const* d_in, const int* in_sizes, int n_in,
                              void* d_out, int out_size, void* d_ws, size_t ws_size,
                              hipStream_t stream) {
  const float* x  = (const float*)d_in[0];
  const int*   mp = (const int*)d_in[1];
  const float* wg = (const float*)d_in[2];
  const float* w1 = (const float*)d_in[3];
  const float* b1 = (const float*)d_in[4];
  const float* w2 = (const float*)d_in[5];
  const float* b2 = (const float*)d_in[6];
  float* out = (float*)d_out;
  char* ws = (char*)d_ws;

  float* p    = (float*)(ws + 0);            // 65536
  int*   cnt  = (int*)(ws + 65536);          // 32
  int*   idxl = (int*)(ws + 66048);          // 65536
  int*   tke  = (int*)(ws + 131584);         // 16384
  int*   tks  = (int*)(ws + 147968);         // 16384
  float* tkw  = (float*)(ws + 164352);       // 16384
  size_t off = 180736;
  unsigned short* w1t = (unsigned short*)(ws + off);  off += 67108864;
  unsigned short* w2t = (unsigned short*)(ws + off);  off += 67108864;
  unsigned short* xg  = (unsigned short*)(ws + off);  off += 10485760;   // 5120*1024*2
  unsigned short* h   = (unsigned short*)(ws + off);  off += 41943040;   // 5120*4096*2
  unsigned short* ya  = (unsigned short*)(ws + off);  off += 10485760;   // 5120*1024*2

  hipMemsetAsync(cnt, 0, 32, stream);

  k_gating<<<512, 256, 0, stream>>>(x, wg, p);
  k_softmax<<<NE, 256, 0, stream>>>(p);
  k_route<<<NE, 256, 0, stream>>>(mp, p, cnt, idxl, tke, tks, tkw);
  k_transtile<<<8192, 256, 0, stream>>>(w1, w1t, w2, w2t);
  k_gather<<<dim3(N_TOK, NE), 128, 0, stream>>>(x, cnt, idxl, xg);
  k_gemm1<<<8192, 256, 0, stream>>>(xg, w1t, b1, cnt, h);
  k_gemm2<<<80 * 16, 256, 0, stream>>>(h, w2t, cnt, ya);
  k_combine<<<N_TOK, 256, 0, stream>>>(ya, b2, cnt, tke, tks, tkw, out);
}

// Round 8
// 475.020 us; speedup vs baseline: 1.1852x; 1.0358x over previous
//
#include <hip/hip_runtime.h>

#define N_TOK 2048
#define HD    1024
#define FD    4096
#define NE    8

typedef __attribute__((ext_vector_type(8))) short short8;
typedef __attribute__((ext_vector_type(4))) float floatx4;

// ---------- helpers ----------
__device__ __forceinline__ unsigned short f2bf(float f) {
  unsigned int u = __float_as_uint(f);
  u += 0x7fffu + ((u >> 16) & 1u);   // RNE
  return (unsigned short)(u >> 16);
}

__device__ __forceinline__ void gl2lds16(const unsigned short* g, unsigned short* l) {
  __builtin_amdgcn_global_load_lds(
      (const __attribute__((address_space(1))) unsigned int*)g,
      (__attribute__((address_space(3))) unsigned int*)l, 16, 0, 0);
}

__device__ __forceinline__ float gelu_tanh(float x) {
  float t = 0.7978845608028654f * x * (1.0f + 0.044715f * x * x);
  return 0.5f * x * (1.0f + tanhf(t));
}

__device__ __forceinline__ int poff_of(const int* __restrict__ cnt, int e) {
  int o = 0;
  for (int i = 0; i < e; ++i) o += (cnt[i] + 127) & ~127;
  return o;
}

// ---------- gating (+ cnt zeroing; cnt only read by later dispatches) ----------
__global__ void k_gating(const float* __restrict__ x, const float* __restrict__ wg,
                         float* __restrict__ p, int* __restrict__ cnt) {
  if (blockIdx.x == 0 && threadIdx.x < NE) cnt[threadIdx.x] = 0;
  int wave = threadIdx.x >> 6;
  int lane = threadIdx.x & 63;
  int n = blockIdx.x * 4 + wave;
  const float4* xr = (const float4*)(x + (size_t)n * HD);
  float4 xv[4];
  #pragma unroll
  for (int i = 0; i < 4; ++i) xv[i] = xr[lane + i * 64];
  for (int e = 0; e < NE; ++e) {
    const float4* wr = (const float4*)(wg + (size_t)e * HD);
    float s = 0.f;
    #pragma unroll
    for (int i = 0; i < 4; ++i) {
      float4 w4 = wr[lane + i * 64];
      s += xv[i].x * w4.x + xv[i].y * w4.y + xv[i].z * w4.z + xv[i].w * w4.w;
    }
    for (int o = 32; o > 0; o >>= 1) s += __shfl_xor(s, o, 64);
    if (lane == 0) p[e * N_TOK + n] = s;
  }
}

// ---------- softmax stats + route, single block (replaces 2 dispatches) ----------
// Never materializes normalized p: computes per-expert (max, 1/sum), then
// routes with LDS counters. Same arithmetic as the old softmax+route pair.
__global__ __launch_bounds__(1024) void k_smroute(
    const float* __restrict__ p, const int* __restrict__ mp,
    int* __restrict__ cnt, int* __restrict__ idxl,
    int* __restrict__ tke, int* __restrict__ tks, float* __restrict__ tkw) {
  __shared__ float red[1024];
  __shared__ float ms[NE], is[NE];
  __shared__ int cntL[NE];
  const int t = threadIdx.x;
  const int e = t >> 7;          // 0..7: expert group of 128 threads
  const int g = t & 127;
  const float* col = p + e * N_TOK;

  // per-expert max
  float m = -1e30f;
  #pragma unroll
  for (int i = 0; i < 16; ++i) m = fmaxf(m, col[g + (i << 7)]);
  red[t] = m; __syncthreads();
  for (int s = 64; s > 0; s >>= 1) {
    if (g < s) red[t] = fmaxf(red[t], red[t + s]);
    __syncthreads();
  }
  if (g == 0) ms[e] = red[t];
  __syncthreads();
  m = ms[e];

  // per-expert sum of exp
  float sum = 0.f;
  #pragma unroll
  for (int i = 0; i < 16; ++i) sum += expf(col[g + (i << 7)] - m);
  red[t] = sum; __syncthreads();
  for (int s = 64; s > 0; s >>= 1) {
    if (g < s) red[t] += red[t + s];
    __syncthreads();
  }
  if (g == 0) is[e] = 1.0f / red[t];
  if (t < NE) cntL[t] = 0;
  __syncthreads();

  // route: tokens t and t+1024, LDS counters
  #pragma unroll
  for (int i = 0; i < 2; ++i) {
    int n = t + (i << 10);
    int m0 = mp[n * 2 + 0], m1 = mp[n * 2 + 1];
    if (m0 == m1) {
      int s = atomicAdd(&cntL[m0], 1);
      idxl[m0 * N_TOK + s] = n;
      tke[n * 2] = m0; tks[n * 2] = s; tkw[n * 2] = 1.0f;
      tke[n * 2 + 1] = m0; tks[n * 2 + 1] = s; tkw[n * 2 + 1] = 0.0f;
    } else {
      float p0 = expf(p[m0 * N_TOK + n] - ms[m0]) * is[m0];
      float p1 = expf(p[m1 * N_TOK + n] - ms[m1]) * is[m1];
      float inv = 1.0f / (p0 + p1);
      int s0 = atomicAdd(&cntL[m0], 1);
      idxl[m0 * N_TOK + s0] = n;
      tke[n * 2] = m0; tks[n * 2] = s0; tkw[n * 2] = p0 * inv;
      int s1 = atomicAdd(&cntL[m1], 1);
      idxl[m1 * N_TOK + s1] = n;
      tke[n * 2 + 1] = m1; tks[n * 2 + 1] = s1; tkw[n * 2 + 1] = p1 * inv;
    }
  }
  __syncthreads();
  if (t < NE) cnt[t] = cntL[t];
}

// ---------- gather x rows -> bf16 arena ----------
__global__ void k_gather(const float* __restrict__ x, const int* __restrict__ cnt,
                         const int* __restrict__ idxl, unsigned short* __restrict__ xg) {
  int e = blockIdx.y;
  int r = blockIdx.x;
  int c = cnt[e];
  int pc = (c + 127) & ~127;
  if (r >= pc) return;
  unsigned short* dst = xg + ((size_t)poff_of(cnt, e) + r) * HD;
  int t = threadIdx.x;
  union { unsigned short us[8]; uint4 v; } o;
  if (r < c) {
    const float* src = x + (size_t)idxl[e * N_TOK + r] * HD;
    float4 f0 = ((const float4*)src)[t * 2];
    float4 f1 = ((const float4*)src)[t * 2 + 1];
    o.us[0] = f2bf(f0.x); o.us[1] = f2bf(f0.y); o.us[2] = f2bf(f0.z); o.us[3] = f2bf(f0.w);
    o.us[4] = f2bf(f1.x); o.us[5] = f2bf(f1.y); o.us[6] = f2bf(f1.z); o.us[7] = f2bf(f1.w);
  } else {
    o.v.x = 0u; o.v.y = 0u; o.v.z = 0u; o.v.w = 0u;
  }
  ((uint4*)dst)[t] = o.v;
}

// ---------- transpose+cvt into GEMM-native 8KB tiles, REGISTER transpose ----------
// Layout: w1t[e][nt(32)][kt(32)][128n][32k], w2t[e][nt(8)][kt(128)][128n][32k].
__global__ __launch_bounds__(256) void k_transtile(const float* __restrict__ w1,
                                                   unsigned short* __restrict__ w1t,
                                                   const float* __restrict__ w2,
                                                   unsigned short* __restrict__ w2t) {
  int l = blockIdx.x;
  const float* src; unsigned short* dst; int ncols; size_t tb0, tb1;
  int kt, ng;
  if (l < 4096) {        // W1: K=HD rows, N=FD cols
    int e = l >> 9; kt = (l >> 4) & 31; ng = l & 15;
    src = w1 + (size_t)e * HD * FD; ncols = FD; dst = w1t;
    tb0 = (((size_t)e * 32 + ng * 2 + 0) * 32 + kt) * 4096;
    tb1 = (((size_t)e * 32 + ng * 2 + 1) * 32 + kt) * 4096;
  } else {               // W2: K=FD rows, N=HD cols
    int l2 = l - 4096;
    int e = l2 >> 9; kt = (l2 >> 2) & 127; ng = l2 & 3;
    src = w2 + (size_t)e * FD * HD; ncols = HD; dst = w2t;
    tb0 = (((size_t)e * 8 + ng * 2 + 0) * 128 + kt) * 4096;
    tb1 = (((size_t)e * 8 + ng * 2 + 1) * 128 + kt) * 4096;
  }
  const int t = threadIdx.x;
  const int k0 = (t & 3) * 8;        // k-octet 0..24
  const int n0 = (t >> 2) * 4;       // n 0..252
  const float* s = src + (size_t)(kt * 32 + k0) * ncols + ng * 256 + n0;
  float4 f[8];
  #pragma unroll
  for (int j = 0; j < 8; ++j)
    f[j] = *(const float4*)(s + (size_t)j * ncols);
  size_t tb = (n0 < 128) ? tb0 : tb1;
  unsigned short* d = dst + tb + (size_t)(n0 & 127) * 32 + k0;
  #pragma unroll
  for (int i = 0; i < 4; ++i) {
    union { unsigned short us[8]; uint4 v; } u;
    #pragma unroll
    for (int j = 0; j < 8; ++j) u.us[j] = f2bf(((const float*)&f[j])[i]);
    *(uint4*)(d + (size_t)i * 32) = u.v;
  }
}

// ---------- GEMM1: h = gelu(xg @ W1[e] + b1[e])  (K=1024, tile 64x128) ----------
__global__ __launch_bounds__(256) void k_gemm1(
    const unsigned short* __restrict__ xg, const unsigned short* __restrict__ w1t,
    const float* __restrict__ b1, const int* __restrict__ cnt,
    unsigned short* __restrict__ h) {
  const int l = blockIdx.x;
  const int r = l & 7;
  const int m = (l >> 3) & 31;
  const int q = l >> 8;
  const int e = q >> 2;
  const int n = ((q & 3) << 3) | r;

  const int c = cnt[e];
  const int mbase = m * 64;
  if (mbase >= c) return;
  const int nbase = n * 128;
  const int po = poff_of(cnt, e);
  const unsigned short* A = xg + ((size_t)po + mbase) * HD;
  const unsigned short* Bt = w1t + (((size_t)e * 32 + n) * 32) * 4096;  // tiled B

  __shared__ unsigned short As[64 * 32];
  __shared__ unsigned short Bs[128 * 32];

  const int tid = threadIdx.x;
  const int wave = tid >> 6, lane = tid & 63;
  const int quad = lane >> 4, lrow = lane & 15;
  const int wn = wave * 32;

  floatx4 acc[4][2];
  #pragma unroll
  for (int i = 0; i < 4; ++i)
    #pragma unroll
    for (int j = 0; j < 2; ++j) acc[i][j] = (floatx4){0.f, 0.f, 0.f, 0.f};

  const int rA = tid >> 2, kA = (tid & 3) * 8;

  for (int kt = 0; kt < HD / 32; ++kt) {
    __syncthreads();
    gl2lds16(A + kt * 32 + (size_t)rA * HD + kA, As + (size_t)wave * 512);
    const unsigned short* gb = Bt + (size_t)kt * 4096 + (size_t)tid * 8;
    gl2lds16(gb,        Bs + (size_t)wave * 512);
    gl2lds16(gb + 2048, Bs + 2048 + (size_t)wave * 512);
    __syncthreads();
    short8 aF[4], bF[2];
    #pragma unroll
    for (int i = 0; i < 4; ++i)
      aF[i] = *(const short8*)(As + (i * 16 + lrow) * 32 + quad * 8);
    #pragma unroll
    for (int j = 0; j < 2; ++j)
      bF[j] = *(const short8*)(Bs + (wn + j * 16 + lrow) * 32 + quad * 8);
    #pragma unroll
    for (int i = 0; i < 4; ++i)
      #pragma unroll
      for (int j = 0; j < 2; ++j)
        acc[i][j] = __builtin_amdgcn_mfma_f32_16x16x32_bf16(aF[i], bF[j], acc[i][j], 0, 0, 0);
  }

  const size_t hrow0 = (size_t)po + mbase;
  #pragma unroll
  for (int i = 0; i < 4; ++i) {
    #pragma unroll
    for (int rr = 0; rr < 4; ++rr) {
      int row = i * 16 + quad * 4 + rr;
      unsigned short* hr = h + (hrow0 + row) * FD + nbase;
      #pragma unroll
      for (int j = 0; j < 2; ++j) {
        int col = wn + j * 16 + lrow;
        float v = acc[i][j][rr] + b1[e * FD + nbase + col];
        hr[col] = f2bf(gelu_tanh(v));
      }
    }
  }
}

// ---------- GEMM2: ya = h @ W2[e]  (K=4096, tile 64x64, BK=64) ----------
__global__ __launch_bounds__(256) void k_gemm2(
    const unsigned short* __restrict__ h, const unsigned short* __restrict__ w2t,
    const int* __restrict__ cnt, unsigned short* __restrict__ ya) {
  const int l = blockIdx.x;
  const int nt = l & 15;
  const int mt = l >> 4;
  const int mbase = mt * 64;
  const int nbase = nt * 64;

  // expert lookup over padded row space
  int e = -1, po = 0, ce = 0;
  {
    int o = 0;
    #pragma unroll
    for (int i = 0; i < NE; ++i) {
      int ci = cnt[i];
      int pc = (ci + 127) & ~127;
      if (mbase >= o && mbase < o + pc) { e = i; po = o; ce = ci; }
      o += pc;
    }
  }
  if (e < 0) return;                 // beyond padded total
  if (mbase - po >= ce) return;      // pure pad tile

  const unsigned short* A = h + (size_t)mbase * FD;
  // tiled B: 64-row half (nt&1) of 128-tile (nt>>1)
  const unsigned short* Bt = w2t + (((size_t)e * 8 + (nt >> 1)) * 128) * 4096
                                 + (size_t)(nt & 1) * 2048;

  __shared__ unsigned short As[2 * 64 * 32];   // [c][64m][32k]
  __shared__ unsigned short Bs[2 * 64 * 32];

  const int tid = threadIdx.x;
  const int wave = tid >> 6, lane = tid & 63;
  const int quad = lane >> 4, lrow = lane & 15;
  const int wm = (wave >> 1) * 32, wn = (wave & 1) * 32;

  floatx4 acc[2][2];
  #pragma unroll
  for (int i = 0; i < 2; ++i)
    #pragma unroll
    for (int j = 0; j < 2; ++j) acc[i][j] = (floatx4){0.f, 0.f, 0.f, 0.f};

  const int r0 = tid >> 2, k0 = (tid & 3) * 8;

  for (int kt = 0; kt < FD / 64; ++kt) {
    __syncthreads();
    #pragma unroll
    for (int cc = 0; cc < 2; ++cc) {
      gl2lds16(A + (size_t)r0 * FD + kt * 64 + cc * 32 + k0,
               As + cc * 2048 + (size_t)wave * 512);
      gl2lds16(Bt + (size_t)(kt * 2 + cc) * 4096 + (size_t)tid * 8,
               Bs + cc * 2048 + (size_t)wave * 512);
    }
    __syncthreads();
    #pragma unroll
    for (int cc = 0; cc < 2; ++cc) {
      short8 aF[2], bF[2];
      #pragma unroll
      for (int i = 0; i < 2; ++i)
        aF[i] = *(const short8*)(As + cc * 2048 + (wm + i * 16 + lrow) * 32 + quad * 8);
      #pragma unroll
      for (int j = 0; j < 2; ++j)
        bF[j] = *(const short8*)(Bs + cc * 2048 + (wn + j * 16 + lrow) * 32 + quad * 8);
      #pragma unroll
      for (int i = 0; i < 2; ++i)
        #pragma unroll
        for (int j = 0; j < 2; ++j)
          acc[i][j] = __builtin_amdgcn_mfma_f32_16x16x32_bf16(aF[i], bF[j], acc[i][j], 0, 0, 0);
    }
  }

  #pragma unroll
  for (int i = 0; i < 2; ++i) {
    #pragma unroll
    for (int rr = 0; rr < 4; ++rr) {
      int row = mbase + wm + i * 16 + quad * 4 + rr;
      unsigned short* yr = ya + (size_t)row * HD + nbase;
      #pragma unroll
      for (int j = 0; j < 2; ++j) {
        int col = wn + j * 16 + lrow;
        yr[col] = f2bf(acc[i][j][rr]);
      }
    }
  }
}

// ---------- combine: out[n] = sum_k w_k * (ya[pos_k] + b2[e_k]) ----------
__global__ __launch_bounds__(256) void k_combine(
    const unsigned short* __restrict__ ya, const float* __restrict__ b2,
    const int* __restrict__ cnt, const int* __restrict__ tke,
    const int* __restrict__ tks, const float* __restrict__ tkw,
    float* __restrict__ out) {
  int n = blockIdx.x;
  int e0 = tke[n * 2], e1 = tke[n * 2 + 1];
  int p0 = poff_of(cnt, e0) + tks[n * 2];
  int p1 = poff_of(cnt, e1) + tks[n * 2 + 1];
  float w0 = tkw[n * 2], w1 = tkw[n * 2 + 1];
  int c = threadIdx.x * 4;
  union { unsigned short us[4]; unsigned long long ll; } y0, y1;
  y0.ll = *(const unsigned long long*)(ya + (size_t)p0 * HD + c);
  y1.ll = *(const unsigned long long*)(ya + (size_t)p1 * HD + c);
  float4 bb0 = *(const float4*)(b2 + (size_t)e0 * HD + c);
  float4 bb1 = *(const float4*)(b2 + (size_t)e1 * HD + c);
  float4 o;
  o.x = w0 * (__uint_as_float((unsigned)y0.us[0] << 16) + bb0.x) + w1 * (__uint_as_float((unsigned)y1.us[0] << 16) + bb1.x);
  o.y = w0 * (__uint_as_float((unsigned)y0.us[1] << 16) + bb0.y) + w1 * (__uint_as_float((unsigned)y1.us[1] << 16) + bb1.y);
  o.z = w0 * (__uint_as_float((unsigned)y0.us[2] << 16) + bb0.z) + w1 * (__uint_as_float((unsigned)y1.us[2] << 16) + bb1.z);
  o.w = w0 * (__uint_as_float((unsigned)y0.us[3] << 16) + bb0.w) + w1 * (__uint_as_float((unsigned)y1.us[3] << 16) + bb1.w);
  *(float4*)(out + (size_t)n * HD + c) = o;
}

// ---------- launch ----------
extern "C" void kernel_launch(void* const* d_in, const int* in_sizes, int n_in,
                              void* d_out, int out_size, void* d_ws, size_t ws_size,
                              hipStream_t stream) {
  const float* x  = (const float*)d_in[0];
  const int*   mp = (const int*)d_in[1];
  const float* wg = (const float*)d_in[2];
  const float* w1 = (const float*)d_in[3];
  const float* b1 = (const float*)d_in[4];
  const float* w2 = (const float*)d_in[5];
  const float* b2 = (const float*)d_in[6];
  float* out = (float*)d_out;
  char* ws = (char*)d_ws;

  float* p    = (float*)(ws + 0);            // 65536
  int*   cnt  = (int*)(ws + 65536);          // 32
  int*   idxl = (int*)(ws + 66048);          // 65536
  int*   tke  = (int*)(ws + 131584);         // 16384
  int*   tks  = (int*)(ws + 147968);         // 16384
  float* tkw  = (float*)(ws + 164352);       // 16384
  size_t off = 180736;
  unsigned short* w1t = (unsigned short*)(ws + off);  off += 67108864;
  unsigned short* w2t = (unsigned short*)(ws + off);  off += 67108864;
  unsigned short* xg  = (unsigned short*)(ws + off);  off += 10485760;   // 5120*1024*2
  unsigned short* h   = (unsigned short*)(ws + off);  off += 41943040;   // 5120*4096*2
  unsigned short* ya  = (unsigned short*)(ws + off);  off += 10485760;   // 5120*1024*2

  k_gating<<<512, 256, 0, stream>>>(x, wg, p, cnt);
  k_smroute<<<1, 1024, 0, stream>>>(p, mp, cnt, idxl, tke, tks, tkw);
  k_transtile<<<8192, 256, 0, stream>>>(w1, w1t, w2, w2t);
  k_gather<<<dim3(N_TOK, NE), 128, 0, stream>>>(x, cnt, idxl, xg);
  k_gemm1<<<8192, 256, 0, stream>>>(xg, w1t, b1, cnt, h);
  k_gemm2<<<80 * 16, 256, 0, stream>>>(h, w2t, cnt, ya);
  k_combine<<<N_TOK, 256, 0, stream>>>(ya, b2, cnt, tke, tks, tkw, out);
}

// Round 9
// 471.689 us; speedup vs baseline: 1.1935x; 1.0071x over previous
//
#include <hip/hip_runtime.h>

#define N_TOK 2048
#define HD    1024
#define FD    4096
#define NE    8

typedef __attribute__((ext_vector_type(8))) short short8;
typedef __attribute__((ext_vector_type(4))) float floatx4;

// ---------- helpers ----------
__device__ __forceinline__ unsigned short f2bf(float f) {
  unsigned int u = __float_as_uint(f);
  u += 0x7fffu + ((u >> 16) & 1u);   // RNE
  return (unsigned short)(u >> 16);
}

__device__ __forceinline__ void gl2lds16(const unsigned short* g, unsigned short* l) {
  __builtin_amdgcn_global_load_lds(
      (const __attribute__((address_space(1))) unsigned int*)g,
      (__attribute__((address_space(3))) unsigned int*)l, 16, 0, 0);
}

__device__ __forceinline__ float gelu_tanh(float x) {
  float t = 0.7978845608028654f * x * (1.0f + 0.044715f * x * x);
  return 0.5f * x * (1.0f + tanhf(t));
}

// 64-aligned arena (tiles are 64 rows; pad-to-tile, not 128)
__device__ __forceinline__ int poff_of(const int* __restrict__ cnt, int e) {
  int o = 0;
  for (int i = 0; i < e; ++i) o += (cnt[i] + 63) & ~63;
  return o;
}

// ---------- gating (+ cnt zeroing; smroute rewrites cnt anyway) ----------
__global__ void k_gating(const float* __restrict__ x, const float* __restrict__ wg,
                         float* __restrict__ p, int* __restrict__ cnt) {
  if (blockIdx.x == 0 && threadIdx.x < NE) cnt[threadIdx.x] = 0;
  int wave = threadIdx.x >> 6;
  int lane = threadIdx.x & 63;
  int n = blockIdx.x * 4 + wave;
  const float4* xr = (const float4*)(x + (size_t)n * HD);
  float4 xv[4];
  #pragma unroll
  for (int i = 0; i < 4; ++i) xv[i] = xr[lane + i * 64];
  for (int e = 0; e < NE; ++e) {
    const float4* wr = (const float4*)(wg + (size_t)e * HD);
    float s = 0.f;
    #pragma unroll
    for (int i = 0; i < 4; ++i) {
      float4 w4 = wr[lane + i * 64];
      s += xv[i].x * w4.x + xv[i].y * w4.y + xv[i].z * w4.z + xv[i].w * w4.w;
    }
    for (int o = 32; o > 0; o >>= 1) s += __shfl_xor(s, o, 64);
    if (lane == 0) p[e * N_TOK + n] = s;
  }
}

// ---------- softmax stats + route, single block ----------
__global__ __launch_bounds__(1024) void k_smroute(
    const float* __restrict__ p, const int* __restrict__ mp,
    int* __restrict__ cnt, int* __restrict__ idxl,
    int* __restrict__ tke, int* __restrict__ tks, float* __restrict__ tkw) {
  __shared__ float red[1024];
  __shared__ float ms[NE], is[NE];
  __shared__ int cntL[NE];
  const int t = threadIdx.x;
  const int e = t >> 7;          // 0..7: expert group of 128 threads
  const int g = t & 127;
  const float* col = p + e * N_TOK;

  // per-expert max
  float m = -1e30f;
  #pragma unroll
  for (int i = 0; i < 16; ++i) m = fmaxf(m, col[g + (i << 7)]);
  red[t] = m; __syncthreads();
  for (int s = 64; s > 0; s >>= 1) {
    if (g < s) red[t] = fmaxf(red[t], red[t + s]);
    __syncthreads();
  }
  if (g == 0) ms[e] = red[t];
  __syncthreads();
  m = ms[e];

  // per-expert sum of exp
  float sum = 0.f;
  #pragma unroll
  for (int i = 0; i < 16; ++i) sum += expf(col[g + (i << 7)] - m);
  red[t] = sum; __syncthreads();
  for (int s = 64; s > 0; s >>= 1) {
    if (g < s) red[t] += red[t + s];
    __syncthreads();
  }
  if (g == 0) is[e] = 1.0f / red[t];
  if (t < NE) cntL[t] = 0;
  __syncthreads();

  // route: tokens t and t+1024, LDS counters
  #pragma unroll
  for (int i = 0; i < 2; ++i) {
    int n = t + (i << 10);
    int m0 = mp[n * 2 + 0], m1 = mp[n * 2 + 1];
    if (m0 == m1) {
      int s = atomicAdd(&cntL[m0], 1);
      idxl[m0 * N_TOK + s] = n;
      tke[n * 2] = m0; tks[n * 2] = s; tkw[n * 2] = 1.0f;
      tke[n * 2 + 1] = m0; tks[n * 2 + 1] = s; tkw[n * 2 + 1] = 0.0f;
    } else {
      float p0 = expf(p[m0 * N_TOK + n] - ms[m0]) * is[m0];
      float p1 = expf(p[m1 * N_TOK + n] - ms[m1]) * is[m1];
      float inv = 1.0f / (p0 + p1);
      int s0 = atomicAdd(&cntL[m0], 1);
      idxl[m0 * N_TOK + s0] = n;
      tke[n * 2] = m0; tks[n * 2] = s0; tkw[n * 2] = p0 * inv;
      int s1 = atomicAdd(&cntL[m1], 1);
      idxl[m1 * N_TOK + s1] = n;
      tke[n * 2 + 1] = m1; tks[n * 2 + 1] = s1; tkw[n * 2 + 1] = p1 * inv;
    }
  }
  __syncthreads();
  if (t < NE) cnt[t] = cntL[t];
}

// ---------- prep: transtile (blocks 0..8191) + gather (blocks 8192..16383) ----------
// transtile: w1t[e][nt(32)][kt(32)][128n][32k], w2t[e][nt(8)][kt(128)][128n][32k];
// register transpose, no LDS. gather: x rows -> bf16 arena, 2 rows/block.
__global__ __launch_bounds__(256) void k_prep(
    const float* __restrict__ w1, unsigned short* __restrict__ w1t,
    const float* __restrict__ w2, unsigned short* __restrict__ w2t,
    const float* __restrict__ x, const int* __restrict__ cnt,
    const int* __restrict__ idxl, unsigned short* __restrict__ xg) {
  int l = blockIdx.x;
  if (l >= 8192) {
    // ---- gather half ----
    int base = (l - 8192) * 2 + (threadIdx.x >> 7);
    int e = base >> 11, r = base & 2047;
    int c = cnt[e];
    int pc = (c + 63) & ~63;
    if (r >= pc) return;
    unsigned short* dst = xg + ((size_t)poff_of(cnt, e) + r) * HD;
    int t = threadIdx.x & 127;
    union { unsigned short us[8]; uint4 v; } o;
    if (r < c) {
      const float* src = x + (size_t)idxl[e * N_TOK + r] * HD;
      float4 f0 = ((const float4*)src)[t * 2];
      float4 f1 = ((const float4*)src)[t * 2 + 1];
      o.us[0] = f2bf(f0.x); o.us[1] = f2bf(f0.y); o.us[2] = f2bf(f0.z); o.us[3] = f2bf(f0.w);
      o.us[4] = f2bf(f1.x); o.us[5] = f2bf(f1.y); o.us[6] = f2bf(f1.z); o.us[7] = f2bf(f1.w);
    } else {
      o.v.x = 0u; o.v.y = 0u; o.v.z = 0u; o.v.w = 0u;
    }
    ((uint4*)dst)[t] = o.v;
    return;
  }
  // ---- transtile half ----
  const float* src; unsigned short* dst; int ncols; size_t tb0, tb1;
  int kt, ng;
  if (l < 4096) {        // W1: K=HD rows, N=FD cols
    int e = l >> 9; kt = (l >> 4) & 31; ng = l & 15;
    src = w1 + (size_t)e * HD * FD; ncols = FD; dst = w1t;
    tb0 = (((size_t)e * 32 + ng * 2 + 0) * 32 + kt) * 4096;
    tb1 = (((size_t)e * 32 + ng * 2 + 1) * 32 + kt) * 4096;
  } else {               // W2: K=FD rows, N=HD cols
    int l2 = l - 4096;
    int e = l2 >> 9; kt = (l2 >> 2) & 127; ng = l2 & 3;
    src = w2 + (size_t)e * FD * HD; ncols = HD; dst = w2t;
    tb0 = (((size_t)e * 8 + ng * 2 + 0) * 128 + kt) * 4096;
    tb1 = (((size_t)e * 8 + ng * 2 + 1) * 128 + kt) * 4096;
  }
  const int t = threadIdx.x;
  const int k0 = (t & 3) * 8;        // k-octet 0..24
  const int n0 = (t >> 2) * 4;       // n 0..252
  const float* s = src + (size_t)(kt * 32 + k0) * ncols + ng * 256 + n0;
  float4 f[8];
  #pragma unroll
  for (int j = 0; j < 8; ++j)
    f[j] = *(const float4*)(s + (size_t)j * ncols);
  size_t tb = (n0 < 128) ? tb0 : tb1;
  unsigned short* d = dst + tb + (size_t)(n0 & 127) * 32 + k0;
  #pragma unroll
  for (int i = 0; i < 4; ++i) {
    union { unsigned short us[8]; uint4 v; } u;
    #pragma unroll
    for (int j = 0; j < 8; ++j) u.us[j] = f2bf(((const float*)&f[j])[i]);
    *(uint4*)(d + (size_t)i * 32) = u.v;
  }
}

// ---------- GEMM1: h = gelu(xg @ W1[e] + b1[e])  (K=1024, tile 64x128) ----------
__global__ __launch_bounds__(256) void k_gemm1(
    const unsigned short* __restrict__ xg, const unsigned short* __restrict__ w1t,
    const float* __restrict__ b1, const int* __restrict__ cnt,
    unsigned short* __restrict__ h) {
  const int l = blockIdx.x;
  const int r = l & 7;
  const int m = (l >> 3) & 31;
  const int q = l >> 8;
  const int e = q >> 2;
  const int n = ((q & 3) << 3) | r;

  const int c = cnt[e];
  const int mbase = m * 64;
  if (mbase >= c) return;
  const int nbase = n * 128;
  const int po = poff_of(cnt, e);
  const unsigned short* A = xg + ((size_t)po + mbase) * HD;
  const unsigned short* Bt = w1t + (((size_t)e * 32 + n) * 32) * 4096;  // tiled B

  __shared__ unsigned short As[64 * 32];
  __shared__ unsigned short Bs[128 * 32];

  const int tid = threadIdx.x;
  const int wave = tid >> 6, lane = tid & 63;
  const int quad = lane >> 4, lrow = lane & 15;
  const int wn = wave * 32;

  floatx4 acc[4][2];
  #pragma unroll
  for (int i = 0; i < 4; ++i)
    #pragma unroll
    for (int j = 0; j < 2; ++j) acc[i][j] = (floatx4){0.f, 0.f, 0.f, 0.f};

  const int rA = tid >> 2, kA = (tid & 3) * 8;

  for (int kt = 0; kt < HD / 32; ++kt) {
    __syncthreads();
    gl2lds16(A + kt * 32 + (size_t)rA * HD + kA, As + (size_t)wave * 512);
    const unsigned short* gb = Bt + (size_t)kt * 4096 + (size_t)tid * 8;
    gl2lds16(gb,        Bs + (size_t)wave * 512);
    gl2lds16(gb + 2048, Bs + 2048 + (size_t)wave * 512);
    __syncthreads();
    short8 aF[4], bF[2];
    #pragma unroll
    for (int i = 0; i < 4; ++i)
      aF[i] = *(const short8*)(As + (i * 16 + lrow) * 32 + quad * 8);
    #pragma unroll
    for (int j = 0; j < 2; ++j)
      bF[j] = *(const short8*)(Bs + (wn + j * 16 + lrow) * 32 + quad * 8);
    #pragma unroll
    for (int i = 0; i < 4; ++i)
      #pragma unroll
      for (int j = 0; j < 2; ++j)
        acc[i][j] = __builtin_amdgcn_mfma_f32_16x16x32_bf16(aF[i], bF[j], acc[i][j], 0, 0, 0);
  }

  const size_t hrow0 = (size_t)po + mbase;
  #pragma unroll
  for (int i = 0; i < 4; ++i) {
    #pragma unroll
    for (int rr = 0; rr < 4; ++rr) {
      int row = i * 16 + quad * 4 + rr;
      unsigned short* hr = h + (hrow0 + row) * FD + nbase;
      #pragma unroll
      for (int j = 0; j < 2; ++j) {
        int col = wn + j * 16 + lrow;
        float v = acc[i][j][rr] + b1[e * FD + nbase + col];
        hr[col] = f2bf(gelu_tanh(v));
      }
    }
  }
}

// ---------- GEMM2: ya = h @ W2[e]  (K=4096, tile 64x64, BK=64) ----------
__global__ __launch_bounds__(256) void k_gemm2(
    const unsigned short* __restrict__ h, const unsigned short* __restrict__ w2t,
    const int* __restrict__ cnt, unsigned short* __restrict__ ya) {
  const int l = blockIdx.x;
  const int nt = l & 15;
  const int mt = l >> 4;
  const int mbase = mt * 64;
  const int nbase = nt * 64;

  // expert lookup over padded row space (64-aligned)
  int e = -1, po = 0, ce = 0;
  {
    int o = 0;
    #pragma unroll
    for (int i = 0; i < NE; ++i) {
      int ci = cnt[i];
      int pc = (ci + 63) & ~63;
      if (mbase >= o && mbase < o + pc) { e = i; po = o; ce = ci; }
      o += pc;
    }
  }
  if (e < 0) return;                 // beyond padded total
  if (mbase - po >= ce) return;      // pure pad tile

  const unsigned short* A = h + (size_t)mbase * FD;
  // tiled B: 64-row half (nt&1) of 128-tile (nt>>1)
  const unsigned short* Bt = w2t + (((size_t)e * 8 + (nt >> 1)) * 128) * 4096
                                 + (size_t)(nt & 1) * 2048;

  __shared__ unsigned short As[2 * 64 * 32];   // [c][64m][32k]
  __shared__ unsigned short Bs[2 * 64 * 32];

  const int tid = threadIdx.x;
  const int wave = tid >> 6, lane = tid & 63;
  const int quad = lane >> 4, lrow = lane & 15;
  const int wm = (wave >> 1) * 32, wn = (wave & 1) * 32;

  floatx4 acc[2][2];
  #pragma unroll
  for (int i = 0; i < 2; ++i)
    #pragma unroll
    for (int j = 0; j < 2; ++j) acc[i][j] = (floatx4){0.f, 0.f, 0.f, 0.f};

  const int r0 = tid >> 2, k0 = (tid & 3) * 8;

  for (int kt = 0; kt < FD / 64; ++kt) {
    __syncthreads();
    #pragma unroll
    for (int cc = 0; cc < 2; ++cc) {
      gl2lds16(A + (size_t)r0 * FD + kt * 64 + cc * 32 + k0,
               As + cc * 2048 + (size_t)wave * 512);
      gl2lds16(Bt + (size_t)(kt * 2 + cc) * 4096 + (size_t)tid * 8,
               Bs + cc * 2048 + (size_t)wave * 512);
    }
    __syncthreads();
    #pragma unroll
    for (int cc = 0; cc < 2; ++cc) {
      short8 aF[2], bF[2];
      #pragma unroll
      for (int i = 0; i < 2; ++i)
        aF[i] = *(const short8*)(As + cc * 2048 + (wm + i * 16 + lrow) * 32 + quad * 8);
      #pragma unroll
      for (int j = 0; j < 2; ++j)
        bF[j] = *(const short8*)(Bs + cc * 2048 + (wn + j * 16 + lrow) * 32 + quad * 8);
      #pragma unroll
      for (int i = 0; i < 2; ++i)
        #pragma unroll
        for (int j = 0; j < 2; ++j)
          acc[i][j] = __builtin_amdgcn_mfma_f32_16x16x32_bf16(aF[i], bF[j], acc[i][j], 0, 0, 0);
    }
  }

  #pragma unroll
  for (int i = 0; i < 2; ++i) {
    #pragma unroll
    for (int rr = 0; rr < 4; ++rr) {
      int row = mbase + wm + i * 16 + quad * 4 + rr;
      unsigned short* yr = ya + (size_t)row * HD + nbase;
      #pragma unroll
      for (int j = 0; j < 2; ++j) {
        int col = wn + j * 16 + lrow;
        yr[col] = f2bf(acc[i][j][rr]);
      }
    }
  }
}

// ---------- combine: out[n] = sum_k w_k * (ya[pos_k] + b2[e_k]) ----------
__global__ __launch_bounds__(256) void k_combine(
    const unsigned short* __restrict__ ya, const float* __restrict__ b2,
    const int* __restrict__ cnt, const int* __restrict__ tke,
    const int* __restrict__ tks, const float* __restrict__ tkw,
    float* __restrict__ out) {
  int n = blockIdx.x;
  int e0 = tke[n * 2], e1 = tke[n * 2 + 1];
  int p0 = poff_of(cnt, e0) + tks[n * 2];
  int p1 = poff_of(cnt, e1) + tks[n * 2 + 1];
  float w0 = tkw[n * 2], w1 = tkw[n * 2 + 1];
  int c = threadIdx.x * 4;
  union { unsigned short us[4]; unsigned long long ll; } y0, y1;
  y0.ll = *(const unsigned long long*)(ya + (size_t)p0 * HD + c);
  y1.ll = *(const unsigned long long*)(ya + (size_t)p1 * HD + c);
  float4 bb0 = *(const float4*)(b2 + (size_t)e0 * HD + c);
  float4 bb1 = *(const float4*)(b2 + (size_t)e1 * HD + c);
  float4 o;
  o.x = w0 * (__uint_as_float((unsigned)y0.us[0] << 16) + bb0.x) + w1 * (__uint_as_float((unsigned)y1.us[0] << 16) + bb1.x);
  o.y = w0 * (__uint_as_float((unsigned)y0.us[1] << 16) + bb0.y) + w1 * (__uint_as_float((unsigned)y1.us[1] << 16) + bb1.y);
  o.z = w0 * (__uint_as_float((unsigned)y0.us[2] << 16) + bb0.z) + w1 * (__uint_as_float((unsigned)y1.us[2] << 16) + bb1.z);
  o.w = w0 * (__uint_as_float((unsigned)y0.us[3] << 16) + bb0.w) + w1 * (__uint_as_float((unsigned)y1.us[3] << 16) + bb1.w);
  *(float4*)(out + (size_t)n * HD + c) = o;
}

// ---------- launch ----------
extern "C" void kernel_launch(void* const* d_in, const int* in_sizes, int n_in,
                              void* d_out, int out_size, void* d_ws, size_t ws_size,
                              hipStream_t stream) {
  const float* x  = (const float*)d_in[0];
  const int*   mp = (const int*)d_in[1];
  const float* wg = (const float*)d_in[2];
  const float* w1 = (const float*)d_in[3];
  const float* b1 = (const float*)d_in[4];
  const float* w2 = (const float*)d_in[5];
  const float* b2 = (const float*)d_in[6];
  float* out = (float*)d_out;
  char* ws = (char*)d_ws;

  float* p    = (float*)(ws + 0);            // 65536
  int*   cnt  = (int*)(ws + 65536);          // 32
  int*   idxl = (int*)(ws + 66048);          // 65536
  int*   tke  = (int*)(ws + 131584);         // 16384
  int*   tks  = (int*)(ws + 147968);         // 16384
  float* tkw  = (float*)(ws + 164352);       // 16384
  size_t off = 180736;
  unsigned short* w1t = (unsigned short*)(ws + off);  off += 67108864;
  unsigned short* w2t = (unsigned short*)(ws + off);  off += 67108864;
  unsigned short* xg  = (unsigned short*)(ws + off);  off += 10485760;   // 5120*1024*2
  unsigned short* h   = (unsigned short*)(ws + off);  off += 41943040;   // 5120*4096*2
  unsigned short* ya  = (unsigned short*)(ws + off);  off += 10485760;   // 5120*1024*2

  k_gating<<<512, 256, 0, stream>>>(x, wg, p, cnt);
  k_smroute<<<1, 1024, 0, stream>>>(p, mp, cnt, idxl, tke, tks, tkw);
  k_prep<<<16384, 256, 0, stream>>>(w1, w1t, w2, w2t, x, cnt, idxl, xg);
  k_gemm1<<<8192, 256, 0, stream>>>(xg, w1t, b1, cnt, h);
  k_gemm2<<<80 * 16, 256, 0, stream>>>(h, w2t, cnt, ya);
  k_combine<<<N_TOK, 256, 0, stream>>>(ya, b2, cnt, tke, tks, tkw, out);
}